// Round 3
// baseline (1747.917 us; speedup 1.0000x reference)
//
#include <hip/hip_runtime.h>
#include <hip/hip_bf16.h>

#define NB 4
#define NC 256
#define NHW 4096
#define CPG 8
#define GEPS 1e-6f
#define SM_SCALE 0.0625f
#define ITILE 32
#define JTILE 64

typedef __hip_bfloat16 bf16;

__device__ __forceinline__ float u2f(unsigned short u){
  union { unsigned u32; float f; } w; w.u32 = ((unsigned)u) << 16; return w.f;
}
__device__ __forceinline__ bf16  f2b(float v){ return __float2bfloat16(v); }

__device__ __forceinline__ float4 ld4(const float* p){ return *(const float4*)p; }
__device__ __forceinline__ float4 ld4(const bf16* p){
  ushort4 w = *(const ushort4*)p;
  float4 r; r.x = u2f(w.x); r.y = u2f(w.y); r.z = u2f(w.z); r.w = u2f(w.w); return r;
}
__device__ __forceinline__ void st1(float* p, float v){ *p = v; }
__device__ __forceinline__ void st1(bf16* p, float v){ *p = f2b(v); }

// ---------------- GroupNorm stats: one block per (b,g) ----------------
__global__ __launch_bounds__(256)
void gn_stats_kernel(const float* __restrict__ x, float* __restrict__ stats){
  const int bg = blockIdx.x;                      // 0..127 = b*32+g
  const float* p = x + (size_t)bg * (CPG * NHW);  // group channels contiguous
  float s = 0.f, s2 = 0.f;
  for(int i = threadIdx.x * 4; i < CPG * NHW; i += 1024){
    float4 v = *(const float4*)(p + i);
    s  += v.x + v.y + v.z + v.w;
    s2 += v.x*v.x + v.y*v.y + v.z*v.z + v.w*v.w;
  }
  __shared__ float red[256];
  red[threadIdx.x] = s; __syncthreads();
  for(int t = 128; t > 0; t >>= 1){
    if(threadIdx.x < t) red[threadIdx.x] += red[threadIdx.x + t];
    __syncthreads();
  }
  float sum = red[0]; __syncthreads();
  red[threadIdx.x] = s2; __syncthreads();
  for(int t = 128; t > 0; t >>= 1){
    if(threadIdx.x < t) red[threadIdx.x] += red[threadIdx.x + t];
    __syncthreads();
  }
  if(threadIdx.x == 0){
    const float inv_n = 1.f / (float)(CPG * NHW);
    float mean = sum * inv_n;
    float var = red[0] * inv_n - mean * mean;
    if(var < 0.f) var = 0.f;
    stats[bg * 2]     = mean;
    stats[bg * 2 + 1] = rsqrtf(var + GEPS);
  }
}

// ---- 1x1 conv GEMM: T[o,n] = sum_c W[o,c]*srcGN[b,c,n] + bias[o] ----
// fuse_gn: apply (x-mean)*rstd*scale+bias to src while staging.
// mode 0: out[b, o*NHW + n] (+res) ; mode 1: out[b, n*NC + o]
template<typename TSRC, typename TOUT>
__global__ __launch_bounds__(256)
void conv1x1_kernel(const float* __restrict__ W, const TSRC* __restrict__ src,
                    const float* __restrict__ bias, const float* __restrict__ res,
                    const float* __restrict__ stats, const float* __restrict__ gscale,
                    const float* __restrict__ gbias,
                    TOUT* __restrict__ out, int mode, int fuse_gn){
  __shared__ __align__(16) float As[16][68];
  __shared__ __align__(16) float Bs[16][68];
  const int b  = blockIdx.z;
  const int nB = blockIdx.x * 64;
  const int oB = blockIdx.y * 64;
  const TSRC* su = src + (size_t)b * NC * NHW;
  const int tid = threadIdx.x;
  const int tx = tid & 15, ty = tid >> 4;
  const int idx4 = tid * 4;
  const int ar = idx4 >> 4, ac = idx4 & 15;   // A tile coords
  const int bn = idx4 & 63, bc = idx4 >> 6;   // B tile coords
  float acc[4][4] = {{0.f}};
  for(int k0 = 0; k0 < NC; k0 += 16){
    float4 a4w = ld4(W + (size_t)(oB + ar) * NC + k0 + ac);
    As[ac + 0][ar] = a4w.x; As[ac + 1][ar] = a4w.y;
    As[ac + 2][ar] = a4w.z; As[ac + 3][ar] = a4w.w;
    int c = k0 + bc;
    float4 b4 = ld4(su + (size_t)c * NHW + nB + bn);
    if(fuse_gn){
      int bg = (b << 5) | (c >> 3);
      float rstd = stats[bg * 2 + 1];
      float a = rstd * gscale[c];
      float d = gbias[c] - stats[bg * 2] * a;
      b4.x = b4.x * a + d; b4.y = b4.y * a + d;
      b4.z = b4.z * a + d; b4.w = b4.w * a + d;
    }
    *(float4*)&Bs[bc][bn] = b4;
    __syncthreads();
    #pragma unroll
    for(int kk = 0; kk < 16; kk++){
      float4 a4 = *(const float4*)&As[kk][ty * 4];
      float4 q4 = *(const float4*)&Bs[kk][tx * 4];
      float a[4] = {a4.x, a4.y, a4.z, a4.w};
      float bb[4] = {q4.x, q4.y, q4.z, q4.w};
      #pragma unroll
      for(int r = 0; r < 4; r++)
        #pragma unroll
        for(int s = 0; s < 4; s++) acc[r][s] += a[r] * bb[s];
    }
    __syncthreads();
  }
  float bias4[4];
  #pragma unroll
  for(int r = 0; r < 4; r++) bias4[r] = bias[oB + ty * 4 + r];
  if(mode == 0){
    TOUT* ob = out + (size_t)b * NC * NHW;
    const float* rb = res ? res + (size_t)b * NC * NHW : nullptr;
    #pragma unroll
    for(int r = 0; r < 4; r++){
      int o = oB + ty * 4 + r;
      #pragma unroll
      for(int s = 0; s < 4; s++){
        int n = nB + tx * 4 + s;
        float vv = acc[r][s] + bias4[r];
        if(rb) vv += rb[(size_t)o * NHW + n];
        st1(ob + (size_t)o * NHW + n, vv);
      }
    }
  } else {
    TOUT* ob = out + (size_t)b * NHW * NC;
    #pragma unroll
    for(int s = 0; s < 4; s++){
      int n = nB + tx * 4 + s;
      #pragma unroll
      for(int r = 0; r < 4; r++)
        st1(ob + (size_t)n * NC + oB + ty * 4 + r, acc[r][s] + bias4[r]);
    }
  }
}

// ---------------- fused flash attention ----------------
// q: [B, n, C]  k,v: [B, C, n]  attn out: [B, C, n]  (all bf16)
// block = (i-tile of 32 rows, batch); 256 threads (tx 0..15, ty 0..15)
__global__ __launch_bounds__(256)
void flash_kernel(const bf16* __restrict__ qg, const bf16* __restrict__ kg,
                  const bf16* __restrict__ vg, bf16* __restrict__ attn){
  const int b  = blockIdx.y;
  const int i0 = blockIdx.x * ITILE;
  const int tid = threadIdx.x;
  const int tx = tid & 15, ty = tid >> 4;

  __shared__ unsigned short qT[NC][ITILE];     // [c][i]   16 KB
  __shared__ unsigned short kv[NC][66];        // [c][jj] pad->odd word stride, 33 KB
  __shared__ float Stile[ITILE][65];           // 8.3 KB
  __shared__ float mrow[ITILE], lrow[ITILE], arow[ITILE];
  __shared__ float partial[ITILE][8];

  const unsigned short* qb = (const unsigned short*)qg + ((size_t)b * NHW + i0) * NC;
  const unsigned short* kb = (const unsigned short*)kg + (size_t)b * NC * NHW;
  const unsigned short* vb = (const unsigned short*)vg + (size_t)b * NC * NHW;

  { // load q tile transposed: qT[c][i]
    int i  = tid >> 3;            // 0..31
    int c0 = (tid & 7) * 32;
    #pragma unroll
    for(int cc = 0; cc < 32; cc += 4){
      ushort4 w = *(const ushort4*)(qb + i * NC + c0 + cc);
      qT[c0+cc+0][i] = w.x; qT[c0+cc+1][i] = w.y;
      qT[c0+cc+2][i] = w.z; qT[c0+cc+3][i] = w.w;
    }
  }
  if(tid < ITILE){ mrow[tid] = -1e30f; lrow[tid] = 0.f; }

  float acc0[16], acc1[16];
  #pragma unroll
  for(int cc = 0; cc < 16; cc++){ acc0[cc] = 0.f; acc1[cc] = 0.f; }

  const int jj2   = (tid & 31) * 2;  // staging col
  const int crow0 = tid >> 5;        // staging row base (0..7)

  for(int j0 = 0; j0 < NHW; j0 += JTILE){
    __syncthreads();                         // kv free (prev PV done)
    for(int r = 0; r < 32; r++){             // k tile -> kv
      int c = crow0 + r * 8;
      ushort2 w = *(const ushort2*)(kb + (size_t)c * NHW + j0 + jj2);
      *(ushort2*)&kv[c][jj2] = w;
    }
    __syncthreads();
    { // S tile: rows ty*2+{0,1}, cols tx*4..+3
      float s00=0,s01=0,s02=0,s03=0,s10=0,s11=0,s12=0,s13=0;
      for(int c = 0; c < NC; c++){
        ushort2 qa = *(const ushort2*)&qT[c][ty*2];
        ushort2 ka = *(const ushort2*)&kv[c][tx*4];
        ushort2 kc = *(const ushort2*)&kv[c][tx*4+2];
        float q0 = u2f(qa.x), q1 = u2f(qa.y);
        float k0f = u2f(ka.x), k1f = u2f(ka.y), k2f = u2f(kc.x), k3f = u2f(kc.y);
        s00 += q0*k0f; s01 += q0*k1f; s02 += q0*k2f; s03 += q0*k3f;
        s10 += q1*k0f; s11 += q1*k1f; s12 += q1*k2f; s13 += q1*k3f;
      }
      int r0 = ty*2, c0 = tx*4;
      Stile[r0  ][c0  ] = SM_SCALE*s00; Stile[r0  ][c0+1] = SM_SCALE*s01;
      Stile[r0  ][c0+2] = SM_SCALE*s02; Stile[r0  ][c0+3] = SM_SCALE*s03;
      Stile[r0+1][c0  ] = SM_SCALE*s10; Stile[r0+1][c0+1] = SM_SCALE*s11;
      Stile[r0+1][c0+2] = SM_SCALE*s12; Stile[r0+1][c0+3] = SM_SCALE*s13;
    }
    __syncthreads();                         // S done; kv reads done
    for(int r = 0; r < 32; r++){             // v tile -> kv
      int c = crow0 + r * 8;
      ushort2 w = *(const ushort2*)(vb + (size_t)c * NHW + j0 + jj2);
      *(ushort2*)&kv[c][jj2] = w;
    }
    if(tid < ITILE){                          // row max + alpha
      float mx = Stile[tid][0];
      for(int j = 1; j < JTILE; j++) mx = fmaxf(mx, Stile[tid][j]);
      float mnew = fmaxf(mrow[tid], mx);
      arow[tid] = __expf(mrow[tid] - mnew);
      mrow[tid] = mnew;
    }
    __syncthreads();
    { // P = exp(S - m), partial row sums
      int row = tid >> 3, c0 = (tid & 7) * 8;
      float m = mrow[row], s = 0.f;
      #pragma unroll
      for(int t = 0; t < 8; t++){
        float p = __expf(Stile[row][c0 + t] - m);
        Stile[row][c0 + t] = p; s += p;
      }
      partial[row][tid & 7] = s;
    }
    __syncthreads();
    if(tid < ITILE){                          // l update
      float s = 0.f;
      #pragma unroll
      for(int t = 0; t < 8; t++) s += partial[tid][t];
      lrow[tid] = lrow[tid] * arow[tid] + s;
    }
    { // rescale O, accumulate P·V^T  (cols interleaved: c = tx + 16*cc)
      float a0 = arow[ty*2], a1 = arow[ty*2+1];
      #pragma unroll
      for(int cc = 0; cc < 16; cc++){ acc0[cc] *= a0; acc1[cc] *= a1; }
      for(int jj = 0; jj < JTILE; jj++){
        float p0 = Stile[ty*2][jj], p1 = Stile[ty*2+1][jj];
        #pragma unroll
        for(int cc = 0; cc < 16; cc++){
          float vv = u2f(kv[tx + 16*cc][jj]);
          acc0[cc] += p0 * vv; acc1[cc] += p1 * vv;
        }
      }
    }
  }
  __syncthreads();
  {
    float inv0 = 1.f / lrow[ty*2], inv1 = 1.f / lrow[ty*2 + 1];
    #pragma unroll
    for(int cc = 0; cc < 16; cc++){
      int c = tx + 16*cc;
      bf16* ob = attn + ((size_t)b * NC + c) * NHW + i0;
      ob[ty*2]     = f2b(acc0[cc] * inv0);
      ob[ty*2 + 1] = f2b(acc1[cc] * inv1);
    }
  }
}

extern "C" void kernel_launch(void* const* d_in, const int* in_sizes, int n_in,
                              void* d_out, int out_size, void* d_ws, size_t ws_size,
                              hipStream_t stream){
  (void)in_sizes; (void)n_in; (void)out_size; (void)ws_size;
  const float* x        = (const float*)d_in[0];
  const float* gn_scale = (const float*)d_in[1];
  const float* gn_bias  = (const float*)d_in[2];
  const float* wq = (const float*)d_in[3];  const float* bq = (const float*)d_in[4];
  const float* wk = (const float*)d_in[5];  const float* bk = (const float*)d_in[6];
  const float* wv = (const float*)d_in[7];  const float* bv = (const float*)d_in[8];
  const float* wp = (const float*)d_in[9];  const float* bp = (const float*)d_in[10];
  float* out = (float*)d_out;

  char* ws = (char*)d_ws;
  const size_t TEN = (size_t)NB * NC * NHW;          // 4194304 elements
  float* stats = (float*)ws;                          // 1 KB
  bf16* q    = (bf16*)(ws + 1024);
  bf16* k    = (bf16*)(ws + 1024 + 1 * TEN * 2);
  bf16* v    = (bf16*)(ws + 1024 + 2 * TEN * 2);
  bf16* attn = (bf16*)(ws + 1024 + 3 * TEN * 2);      // total ~33.6 MB

  gn_stats_kernel<<<128, 256, 0, stream>>>(x, stats);

  dim3 cgrid(NHW / 64, NC / 64, NB);
  conv1x1_kernel<float, bf16><<<cgrid, 256, 0, stream>>>(
      wq, x, bq, nullptr, stats, gn_scale, gn_bias, q, 1, 1);
  conv1x1_kernel<float, bf16><<<cgrid, 256, 0, stream>>>(
      wk, x, bk, nullptr, stats, gn_scale, gn_bias, k, 0, 1);
  conv1x1_kernel<float, bf16><<<cgrid, 256, 0, stream>>>(
      wv, x, bv, nullptr, stats, gn_scale, gn_bias, v, 0, 1);

  flash_kernel<<<dim3(NHW / ITILE, NB), 256, 0, stream>>>(q, k, v, attn);

  conv1x1_kernel<bf16, float><<<cgrid, 256, 0, stream>>>(
      wp, attn, bp, x, nullptr, nullptr, nullptr, out, 0, 0);
}

// Round 4
// 875.803 us; speedup vs baseline: 1.9958x; 1.9958x over previous
//
#include <hip/hip_runtime.h>
#include <hip/hip_bf16.h>

#define NB 4
#define NC 256
#define NHW 4096
#define CPG 8
#define GEPS 1e-6f
#define SM_SCALE 0.0625f

typedef __hip_bfloat16 bf16;
typedef __attribute__((ext_vector_type(8))) short bf16x8;
typedef __attribute__((ext_vector_type(4))) float f32x4;
typedef __attribute__((ext_vector_type(8))) unsigned short u16x8;

#define MFMA16(A,B,C) __builtin_amdgcn_mfma_f32_16x16x32_bf16(A,B,C,0,0,0)

__device__ __forceinline__ float u2f(unsigned short u){
  union { unsigned u32; float f; } w; w.u32 = ((unsigned)u) << 16; return w.f;
}
__device__ __forceinline__ bf16 f2b(float v){ return __float2bfloat16(v); }
__device__ __forceinline__ unsigned short f2bu(float v){
  bf16 h = __float2bfloat16(v);
  union { bf16 h; unsigned short u; } w; w.h = h; return w.u;
}
__device__ __forceinline__ float4 ld4(const float* p){ return *(const float4*)p; }
__device__ __forceinline__ float4 ld4(const bf16* p){
  ushort4 w = *(const ushort4*)p;
  float4 r; r.x = u2f(w.x); r.y = u2f(w.y); r.z = u2f(w.z); r.w = u2f(w.w); return r;
}
__device__ __forceinline__ void st1(float* p, float v){ *p = v; }
__device__ __forceinline__ void st1(bf16* p, float v){ *p = f2b(v); }

// ---------------- GroupNorm stats: one block per (b,g) ----------------
__global__ __launch_bounds__(256)
void gn_stats_kernel(const float* __restrict__ x, float* __restrict__ stats){
  const int bg = blockIdx.x;
  const float* p = x + (size_t)bg * (CPG * NHW);
  float s = 0.f, s2 = 0.f;
  for(int i = threadIdx.x * 4; i < CPG * NHW; i += 1024){
    float4 v = *(const float4*)(p + i);
    s  += v.x + v.y + v.z + v.w;
    s2 += v.x*v.x + v.y*v.y + v.z*v.z + v.w*v.w;
  }
  __shared__ float red[256];
  red[threadIdx.x] = s; __syncthreads();
  for(int t = 128; t > 0; t >>= 1){
    if(threadIdx.x < t) red[threadIdx.x] += red[threadIdx.x + t];
    __syncthreads();
  }
  float sum = red[0]; __syncthreads();
  red[threadIdx.x] = s2; __syncthreads();
  for(int t = 128; t > 0; t >>= 1){
    if(threadIdx.x < t) red[threadIdx.x] += red[threadIdx.x + t];
    __syncthreads();
  }
  if(threadIdx.x == 0){
    const float inv_n = 1.f / (float)(CPG * NHW);
    float mean = sum * inv_n;
    float var = red[0] * inv_n - mean * mean;
    if(var < 0.f) var = 0.f;
    stats[bg * 2]     = mean;
    stats[bg * 2 + 1] = rsqrtf(var + GEPS);
  }
}

// ---- 1x1 conv GEMM: T[o,n] = sum_c W[o,c]*srcGN[b,c,n] + bias[o] ----
// src_nc=0: src [b][c][n]; src_nc=1: src [b][n][C]
// mode 0: out[b, o*NHW + n] (+res) ; mode 1: out[b, n*NC + o]
template<typename TSRC, typename TOUT>
__global__ __launch_bounds__(256)
void conv1x1_kernel(const float* __restrict__ W, const TSRC* __restrict__ src,
                    const float* __restrict__ bias, const float* __restrict__ res,
                    const float* __restrict__ stats, const float* __restrict__ gscale,
                    const float* __restrict__ gbias,
                    TOUT* __restrict__ out, int mode, int fuse_gn, int src_nc){
  __shared__ __align__(16) float As[16][68];
  __shared__ __align__(16) float Bs[16][68];
  const int b  = blockIdx.z;
  const int nB = blockIdx.x * 64;
  const int oB = blockIdx.y * 64;
  const TSRC* su = src + (size_t)b * NC * NHW;
  const int tid = threadIdx.x;
  const int tx = tid & 15, ty = tid >> 4;
  const int idx4 = tid * 4;
  const int ar = idx4 >> 4, ac = idx4 & 15;   // A tile coords
  const int bn = idx4 & 63, bc = idx4 >> 6;   // B tile coords (src_nc=0)
  const int bn2 = tid & 63, g2 = tid >> 6;    // B tile coords (src_nc=1)
  float acc[4][4] = {{0.f}};
  for(int k0 = 0; k0 < NC; k0 += 16){
    float4 a4w = ld4(W + (size_t)(oB + ar) * NC + k0 + ac);
    As[ac + 0][ar] = a4w.x; As[ac + 1][ar] = a4w.y;
    As[ac + 2][ar] = a4w.z; As[ac + 3][ar] = a4w.w;
    if(src_nc){
      float4 t = ld4(su + (size_t)(nB + bn2) * NC + k0 + g2 * 4);
      Bs[g2*4+0][bn2] = t.x; Bs[g2*4+1][bn2] = t.y;
      Bs[g2*4+2][bn2] = t.z; Bs[g2*4+3][bn2] = t.w;
    } else {
      int c = k0 + bc;
      float4 b4 = ld4(su + (size_t)c * NHW + nB + bn);
      if(fuse_gn){
        int bg = (b << 5) | (c >> 3);
        float rstd = stats[bg * 2 + 1];
        float a = rstd * gscale[c];
        float d = gbias[c] - stats[bg * 2] * a;
        b4.x = b4.x * a + d; b4.y = b4.y * a + d;
        b4.z = b4.z * a + d; b4.w = b4.w * a + d;
      }
      *(float4*)&Bs[bc][bn] = b4;
    }
    __syncthreads();
    #pragma unroll
    for(int kk = 0; kk < 16; kk++){
      float4 a4 = *(const float4*)&As[kk][ty * 4];
      float4 q4 = *(const float4*)&Bs[kk][tx * 4];
      float a[4] = {a4.x, a4.y, a4.z, a4.w};
      float bb[4] = {q4.x, q4.y, q4.z, q4.w};
      #pragma unroll
      for(int r = 0; r < 4; r++)
        #pragma unroll
        for(int s = 0; s < 4; s++) acc[r][s] += a[r] * bb[s];
    }
    __syncthreads();
  }
  float bias4[4];
  #pragma unroll
  for(int r = 0; r < 4; r++) bias4[r] = bias[oB + ty * 4 + r];
  if(mode == 0){
    TOUT* ob = out + (size_t)b * NC * NHW;
    const float* rb = res ? res + (size_t)b * NC * NHW : nullptr;
    #pragma unroll
    for(int r = 0; r < 4; r++){
      int o = oB + ty * 4 + r;
      #pragma unroll
      for(int s = 0; s < 4; s++){
        int n = nB + tx * 4 + s;
        float vv = acc[r][s] + bias4[r];
        if(rb) vv += rb[(size_t)o * NHW + n];
        st1(ob + (size_t)o * NHW + n, vv);
      }
    }
  } else {
    TOUT* ob = out + (size_t)b * NHW * NC;
    #pragma unroll
    for(int s = 0; s < 4; s++){
      int n = nB + tx * 4 + s;
      #pragma unroll
      for(int r = 0; r < 4; r++)
        st1(ob + (size_t)n * NC + oB + ty * 4 + r, acc[r][s] + bias4[r]);
    }
  }
}

// ---------------- MFMA flash attention ----------------
// q: [B][n][C]  kt: [B][n][C]  v: [B][C][n]  attn out: [B][n][C]  (all bf16)
// block: 16 Q rows, 4 waves = 4 j-chunks of 1024; LDS flash-decoding combine.
__global__ __launch_bounds__(256)
void flash_mfma_kernel(const bf16* __restrict__ qg, const bf16* __restrict__ kt,
                       const bf16* __restrict__ vg, bf16* __restrict__ attn){
  const int b  = blockIdx.y;
  const int i0 = blockIdx.x * 16;
  const int tid = threadIdx.x;
  const int wave = tid >> 6, lane = tid & 63;
  const int l15 = lane & 15, quad = lane >> 4;

  __shared__ __align__(16) unsigned short comb[4][4096]; // 32 KB; per-wave: P tile during loop, O partial after
  __shared__ float mS[4][16], lS[4][16];

  unsigned short* Pt = comb[wave];
  const int PLD = 80;                       // u16 row stride: 160 B (16B-aligned)

  // Q fragments resident: A[m=l15][k=quad*8+j] per kstep
  const short* qp = (const short*)qg + ((size_t)b * NHW + i0 + l15) * NC + quad * 8;
  bf16x8 Qf[8];
  #pragma unroll
  for(int ks = 0; ks < 8; ks++) Qf[ks] = *(const bf16x8*)(qp + ks * 32);

  f32x4 O[16];
  #pragma unroll
  for(int ct = 0; ct < 16; ct++) O[ct] = (f32x4){0.f, 0.f, 0.f, 0.f};
  float mr[4] = {-1e30f, -1e30f, -1e30f, -1e30f};
  float lr[4] = {0.f, 0.f, 0.f, 0.f};

  const short* kbase = (const short*)kt + (size_t)b * NHW * NC;
  const short* vbase = (const short*)vg + ((size_t)b * NC + l15) * NHW;

  const int jw = wave * (NHW / 4);
  for(int jt = 0; jt < (NHW / 4) / 64; jt++){
    const int j0 = jw + jt * 64;
    // ---- S = Q·K^T (4 subtiles of 16 cols) ----
    f32x4 S[4];
    #pragma unroll
    for(int st = 0; st < 4; st++){
      S[st] = (f32x4){0.f, 0.f, 0.f, 0.f};
      const short* kp = kbase + (size_t)(j0 + st * 16 + l15) * NC + quad * 8;
      #pragma unroll
      for(int ks = 0; ks < 8; ks++)
        S[st] = MFMA16(Qf[ks], *(const bf16x8*)(kp + ks * 32), S[st]);
    }
    // ---- online softmax (rows quad*4+r, col l15 per subtile) ----
    float alpha[4];
    #pragma unroll
    for(int r = 0; r < 4; r++){
      float s0 = S[0][r] * SM_SCALE, s1 = S[1][r] * SM_SCALE;
      float s2 = S[2][r] * SM_SCALE, s3 = S[3][r] * SM_SCALE;
      float mx = fmaxf(fmaxf(s0, s1), fmaxf(s2, s3));
      #pragma unroll
      for(int off = 1; off < 16; off <<= 1) mx = fmaxf(mx, __shfl_xor(mx, off, 64));
      float mn = fmaxf(mr[r], mx);
      alpha[r] = __expf(mr[r] - mn);
      mr[r] = mn;
      float p0 = __expf(s0 - mn), p1 = __expf(s1 - mn);
      float p2 = __expf(s2 - mn), p3 = __expf(s3 - mn);
      S[0][r] = p0; S[1][r] = p1; S[2][r] = p2; S[3][r] = p3;
      float rs = p0 + p1 + p2 + p3;
      #pragma unroll
      for(int off = 1; off < 16; off <<= 1) rs += __shfl_xor(rs, off, 64);
      lr[r] = lr[r] * alpha[r] + rs;
    }
    // ---- P: D-layout -> LDS -> A-layout ----
    #pragma unroll
    for(int st = 0; st < 4; st++)
      #pragma unroll
      for(int r = 0; r < 4; r++)
        Pt[(quad * 4 + r) * PLD + st * 16 + l15] = f2bu(S[st][r]);
    #pragma unroll
    for(int ct = 0; ct < 16; ct++){
      O[ct][0] *= alpha[0]; O[ct][1] *= alpha[1];
      O[ct][2] *= alpha[2]; O[ct][3] *= alpha[3];
    }
    // ---- O += P·V^T over 16 c-tiles ----
    #pragma unroll
    for(int js = 0; js < 2; js++){
      bf16x8 Pf = *(const bf16x8*)(Pt + l15 * PLD + js * 32 + quad * 8);
      const short* vp = vbase + j0 + js * 32 + quad * 8;
      #pragma unroll
      for(int ct = 0; ct < 16; ct++)
        O[ct] = MFMA16(Pf, *(const bf16x8*)(vp + (size_t)ct * 16 * NHW), O[ct]);
    }
  }
  // ---- per-wave partials to LDS ----
  #pragma unroll
  for(int ct = 0; ct < 16; ct++)
    #pragma unroll
    for(int r = 0; r < 4; r++)
      comb[wave][(quad * 4 + r) * 256 + ct * 16 + l15] = f2bu(O[ct][r]);
  if(l15 == 0){
    #pragma unroll
    for(int r = 0; r < 4; r++){
      mS[wave][quad * 4 + r] = mr[r];
      lS[wave][quad * 4 + r] = lr[r];
    }
  }
  __syncthreads();
  // ---- flash-decoding combine of 4 j-chunks ----
  {
    const int r = tid >> 4, c0 = (tid & 15) * 16;
    float m0 = mS[0][r], m1 = mS[1][r], m2 = mS[2][r], m3 = mS[3][r];
    float mstar = fmaxf(fmaxf(m0, m1), fmaxf(m2, m3));
    float f0 = __expf(m0 - mstar), f1 = __expf(m1 - mstar);
    float f2 = __expf(m2 - mstar), f3 = __expf(m3 - mstar);
    float lstar = f0 * lS[0][r] + f1 * lS[1][r] + f2 * lS[2][r] + f3 * lS[3][r];
    float inv = 1.f / lstar;
    union { u16x8 v; unsigned short e[8]; } oA, oB;
    #pragma unroll
    for(int cc = 0; cc < 8; cc++){
      int c = c0 + cc;
      float s = f0 * u2f(comb[0][r * 256 + c]) + f1 * u2f(comb[1][r * 256 + c])
              + f2 * u2f(comb[2][r * 256 + c]) + f3 * u2f(comb[3][r * 256 + c]);
      oA.e[cc] = f2bu(s * inv);
    }
    #pragma unroll
    for(int cc = 8; cc < 16; cc++){
      int c = c0 + cc;
      float s = f0 * u2f(comb[0][r * 256 + c]) + f1 * u2f(comb[1][r * 256 + c])
              + f2 * u2f(comb[2][r * 256 + c]) + f3 * u2f(comb[3][r * 256 + c]);
      oB.e[cc - 8] = f2bu(s * inv);
    }
    unsigned short* dst = (unsigned short*)attn + ((size_t)b * NHW + i0 + r) * NC + c0;
    *(u16x8*)dst = oA.v;
    *(u16x8*)(dst + 8) = oB.v;
  }
}

extern "C" void kernel_launch(void* const* d_in, const int* in_sizes, int n_in,
                              void* d_out, int out_size, void* d_ws, size_t ws_size,
                              hipStream_t stream){
  (void)in_sizes; (void)n_in; (void)out_size; (void)ws_size;
  const float* x        = (const float*)d_in[0];
  const float* gn_scale = (const float*)d_in[1];
  const float* gn_bias  = (const float*)d_in[2];
  const float* wq = (const float*)d_in[3];  const float* bq = (const float*)d_in[4];
  const float* wk = (const float*)d_in[5];  const float* bk = (const float*)d_in[6];
  const float* wv = (const float*)d_in[7];  const float* bv = (const float*)d_in[8];
  const float* wp = (const float*)d_in[9];  const float* bp = (const float*)d_in[10];
  float* out = (float*)d_out;

  char* ws = (char*)d_ws;
  const size_t TEN = (size_t)NB * NC * NHW;
  float* stats = (float*)ws;
  bf16* q    = (bf16*)(ws + 1024);                    // [B][n][C]
  bf16* k    = (bf16*)(ws + 1024 + 1 * TEN * 2);      // [B][n][C]
  bf16* v    = (bf16*)(ws + 1024 + 2 * TEN * 2);      // [B][C][n]
  bf16* attn = (bf16*)(ws + 1024 + 3 * TEN * 2);      // [B][n][C]

  gn_stats_kernel<<<128, 256, 0, stream>>>(x, stats);

  dim3 cgrid(NHW / 64, NC / 64, NB);
  conv1x1_kernel<float, bf16><<<cgrid, 256, 0, stream>>>(
      wq, x, bq, nullptr, stats, gn_scale, gn_bias, q, 1, 1, 0);
  conv1x1_kernel<float, bf16><<<cgrid, 256, 0, stream>>>(
      wk, x, bk, nullptr, stats, gn_scale, gn_bias, k, 1, 1, 0);
  conv1x1_kernel<float, bf16><<<cgrid, 256, 0, stream>>>(
      wv, x, bv, nullptr, stats, gn_scale, gn_bias, v, 0, 1, 0);

  flash_mfma_kernel<<<dim3(NHW / 16, NB), 256, 0, stream>>>(q, k, v, attn);

  conv1x1_kernel<bf16, float><<<cgrid, 256, 0, stream>>>(
      wp, attn, bp, x, nullptr, nullptr, nullptr, out, 0, 0, 1);
}

// Round 5
// 453.235 us; speedup vs baseline: 3.8565x; 1.9323x over previous
//
#include <hip/hip_runtime.h>
#include <hip/hip_bf16.h>

#define NB 4
#define NC 256
#define NHW 4096
#define CPG 8
#define GEPS 1e-6f

typedef __hip_bfloat16 bf16;
typedef __attribute__((ext_vector_type(8))) short bf16x8;
typedef __attribute__((ext_vector_type(4))) float f32x4;
typedef __attribute__((ext_vector_type(8))) unsigned short u16x8;

#define MFMA16(A,B,C) __builtin_amdgcn_mfma_f32_16x16x32_bf16(A,B,C,0,0,0)

__device__ __forceinline__ float u2f(unsigned short u){
  union { unsigned u32; float f; } w; w.u32 = ((unsigned)u) << 16; return w.f;
}
__device__ __forceinline__ bf16 f2b(float v){ return __float2bfloat16(v); }
__device__ __forceinline__ unsigned short f2bu(float v){
  union { bf16 h; unsigned short u; } w; w.h = __float2bfloat16(v); return w.u;
}
__device__ __forceinline__ float4 ld4(const float* p){ return *(const float4*)p; }
__device__ __forceinline__ float4 ld4(const bf16* p){
  ushort4 w = *(const ushort4*)p;
  float4 r; r.x = u2f(w.x); r.y = u2f(w.y); r.z = u2f(w.z); r.w = u2f(w.w); return r;
}
__device__ __forceinline__ void st1(float* p, float v){ *p = v; }
__device__ __forceinline__ void st1(bf16* p, float v){ *p = f2b(v); }

// ---------------- GroupNorm stats: one block per (b,g) ----------------
__global__ __launch_bounds__(256)
void gn_stats_kernel(const float* __restrict__ x, float* __restrict__ stats){
  const int bg = blockIdx.x;
  const float* p = x + (size_t)bg * (CPG * NHW);
  float s = 0.f, s2 = 0.f;
  for(int i = threadIdx.x * 4; i < CPG * NHW; i += 1024){
    float4 v = *(const float4*)(p + i);
    s  += v.x + v.y + v.z + v.w;
    s2 += v.x*v.x + v.y*v.y + v.z*v.z + v.w*v.w;
  }
  __shared__ float red[256];
  red[threadIdx.x] = s; __syncthreads();
  for(int t = 128; t > 0; t >>= 1){
    if(threadIdx.x < t) red[threadIdx.x] += red[threadIdx.x + t];
    __syncthreads();
  }
  float sum = red[0]; __syncthreads();
  red[threadIdx.x] = s2; __syncthreads();
  for(int t = 128; t > 0; t >>= 1){
    if(threadIdx.x < t) red[threadIdx.x] += red[threadIdx.x + t];
    __syncthreads();
  }
  if(threadIdx.x == 0){
    const float inv_n = 1.f / (float)(CPG * NHW);
    float mean = sum * inv_n;
    float var = red[0] * inv_n - mean * mean;
    if(var < 0.f) var = 0.f;
    stats[bg * 2]     = mean;
    stats[bg * 2 + 1] = rsqrtf(var + GEPS);
  }
}

// ---- 1x1 conv GEMM: T[o,n] = oscale*(sum_c W[o,c]*srcGN[b,c,n] + bias[o]) ----
template<typename TSRC, typename TOUT>
__global__ __launch_bounds__(256)
void conv1x1_kernel(const float* __restrict__ W, const TSRC* __restrict__ src,
                    const float* __restrict__ bias, const float* __restrict__ res,
                    const float* __restrict__ stats, const float* __restrict__ gscale,
                    const float* __restrict__ gbias,
                    TOUT* __restrict__ out, int mode, int fuse_gn, int src_nc,
                    float oscale){
  __shared__ __align__(16) float As[16][68];
  __shared__ __align__(16) float Bs[16][68];
  const int b  = blockIdx.z;
  const int nB = blockIdx.x * 64;
  const int oB = blockIdx.y * 64;
  const TSRC* su = src + (size_t)b * NC * NHW;
  const int tid = threadIdx.x;
  const int tx = tid & 15, ty = tid >> 4;
  const int idx4 = tid * 4;
  const int ar = idx4 >> 4, ac = idx4 & 15;
  const int bn = idx4 & 63, bc = idx4 >> 6;
  const int bn2 = tid & 63, g2 = tid >> 6;
  float acc[4][4] = {{0.f}};
  for(int k0 = 0; k0 < NC; k0 += 16){
    float4 a4w = ld4(W + (size_t)(oB + ar) * NC + k0 + ac);
    As[ac + 0][ar] = a4w.x; As[ac + 1][ar] = a4w.y;
    As[ac + 2][ar] = a4w.z; As[ac + 3][ar] = a4w.w;
    if(src_nc){
      float4 t = ld4(su + (size_t)(nB + bn2) * NC + k0 + g2 * 4);
      Bs[g2*4+0][bn2] = t.x; Bs[g2*4+1][bn2] = t.y;
      Bs[g2*4+2][bn2] = t.z; Bs[g2*4+3][bn2] = t.w;
    } else {
      int c = k0 + bc;
      float4 b4 = ld4(su + (size_t)c * NHW + nB + bn);
      if(fuse_gn){
        int bg = (b << 5) | (c >> 3);
        float rstd = stats[bg * 2 + 1];
        float a = rstd * gscale[c];
        float d = gbias[c] - stats[bg * 2] * a;
        b4.x = b4.x * a + d; b4.y = b4.y * a + d;
        b4.z = b4.z * a + d; b4.w = b4.w * a + d;
      }
      *(float4*)&Bs[bc][bn] = b4;
    }
    __syncthreads();
    #pragma unroll
    for(int kk = 0; kk < 16; kk++){
      float4 a4 = *(const float4*)&As[kk][ty * 4];
      float4 q4 = *(const float4*)&Bs[kk][tx * 4];
      float a[4] = {a4.x, a4.y, a4.z, a4.w};
      float bb[4] = {q4.x, q4.y, q4.z, q4.w};
      #pragma unroll
      for(int r = 0; r < 4; r++)
        #pragma unroll
        for(int s = 0; s < 4; s++) acc[r][s] += a[r] * bb[s];
    }
    __syncthreads();
  }
  float bias4[4];
  #pragma unroll
  for(int r = 0; r < 4; r++) bias4[r] = bias[oB + ty * 4 + r];
  if(mode == 0){
    TOUT* ob = out + (size_t)b * NC * NHW;
    const float* rb = res ? res + (size_t)b * NC * NHW : nullptr;
    #pragma unroll
    for(int r = 0; r < 4; r++){
      int o = oB + ty * 4 + r;
      #pragma unroll
      for(int s = 0; s < 4; s++){
        int n = nB + tx * 4 + s;
        float vv = (acc[r][s] + bias4[r]) * oscale;
        if(rb) vv += rb[(size_t)o * NHW + n];
        st1(ob + (size_t)o * NHW + n, vv);
      }
    }
  } else {
    TOUT* ob = out + (size_t)b * NHW * NC;
    #pragma unroll
    for(int s = 0; s < 4; s++){
      int n = nB + tx * 4 + s;
      #pragma unroll
      for(int r = 0; r < 4; r++)
        st1(ob + (size_t)n * NC + oB + ty * 4 + r, (acc[r][s] + bias4[r]) * oscale);
    }
  }
}

// ---------------- MFMA flash attention, LDS-staged, j-split x2 ----------------
// q,kt: [B][n][C]  v: [B][C][n]  (bf16; q pre-scaled by 1/16)
// block: 64 Q rows (4 waves x 16), j-half of 2048 per block (32 iters of 64).
// Partials (un-normalized O, m, l) to ws; combine kernel finishes.
__global__ __launch_bounds__(256)
void flash_mfma2_kernel(const bf16* __restrict__ qg, const bf16* __restrict__ ktg,
                        const bf16* __restrict__ vg, bf16* __restrict__ Opart,
                        float* __restrict__ mpart, float* __restrict__ lpart){
  const int b  = blockIdx.y;
  const int h  = blockIdx.z;
  const int i0 = blockIdx.x * 64;
  const int tid = threadIdx.x;
  const int wave = tid >> 6, lane = tid & 63;
  const int l15 = lane & 15, quad = lane >> 4;

  __shared__ __align__(16) unsigned short Kt[2048 * 8];      // 32 KB: 64 j x 32 chunks
  __shared__ __align__(16) unsigned short Vt[2048 * 8];      // 32 KB: 256 c x 8 chunks
  __shared__ __align__(16) unsigned short Pt_all[4][16 * 72]; // 9 KB, per-wave P
  unsigned short* Pt = Pt_all[wave];

  // Q fragments resident (16 rows per wave): A[m=l15][k=quad*8+ks*32]
  const int qrow = i0 + wave * 16 + l15;
  const short* qp = (const short*)qg + ((size_t)b * NHW + qrow) * NC + quad * 8;
  bf16x8 Qf[8];
  #pragma unroll
  for(int ks = 0; ks < 8; ks++) Qf[ks] = *(const bf16x8*)(qp + ks * 32);

  f32x4 O[16];
  #pragma unroll
  for(int ct = 0; ct < 16; ct++) O[ct] = (f32x4){0.f, 0.f, 0.f, 0.f};
  float mr[4] = {-1e30f, -1e30f, -1e30f, -1e30f};
  float lr[4] = {0.f, 0.f, 0.f, 0.f};

  const short* kb = (const short*)ktg + ((size_t)b * NHW + h * 2048) * NC;
  const short* vb = (const short*)vg + (size_t)b * NC * NHW + h * 2048;

  // ---- prologue: stage K(0) (coalesced, XOR-swizzled chunks) ----
  #pragma unroll
  for(int t = 0; t < 8; t++){
    int qn = (wave * 8 + t) * 64 + lane;
    int j = qn >> 5, cs = qn & 31, cc = cs ^ (j & 7);
    u16x8 w = *(const u16x8*)(kb + (size_t)j * NC + cc * 8);
    *(u16x8*)&Kt[qn * 8] = w;
  }
  __syncthreads();

  for(int jt = 0; jt < 32; jt++){
    const int j0 = jt * 64;
    // issue V(jt) global loads (drain at barrier #1)
    u16x8 vst[8];
    #pragma unroll
    for(int t = 0; t < 8; t++){
      int qn = (wave * 8 + t) * 64 + lane;
      int c = qn >> 3, jsl = qn & 7, jj = (jsl ^ (c & 7)) * 8;
      vst[t] = *(const u16x8*)(vb + (size_t)c * NHW + j0 + jj);
    }
    // ---- S = Q.K^T from LDS ----
    f32x4 S[4];
    #pragma unroll
    for(int st = 0; st < 4; st++){
      S[st] = (f32x4){0.f, 0.f, 0.f, 0.f};
      const int j = st * 16 + l15;
      #pragma unroll
      for(int ks = 0; ks < 8; ks++){
        int chunk = j * 32 + ((ks * 4 + quad) ^ (j & 7));
        S[st] = MFMA16(Qf[ks], *(const bf16x8*)&Kt[chunk * 8], S[st]);
      }
    }
    // ---- online softmax (rows quad*4+r; cols l15 per subtile) ----
    float alpha[4];
    #pragma unroll
    for(int r = 0; r < 4; r++){
      float s0 = S[0][r], s1 = S[1][r], s2 = S[2][r], s3 = S[3][r];
      float mx = fmaxf(fmaxf(s0, s1), fmaxf(s2, s3));
      #pragma unroll
      for(int off = 1; off < 16; off <<= 1) mx = fmaxf(mx, __shfl_xor(mx, off, 64));
      float mn = fmaxf(mr[r], mx);
      alpha[r] = __expf(mr[r] - mn);
      mr[r] = mn;
      float p0 = __expf(s0 - mn), p1 = __expf(s1 - mn);
      float p2 = __expf(s2 - mn), p3 = __expf(s3 - mn);
      float rs = p0 + p1 + p2 + p3;
      #pragma unroll
      for(int off = 1; off < 16; off <<= 1) rs += __shfl_xor(rs, off, 64);
      lr[r] = lr[r] * alpha[r] + rs;
      int pr = (quad * 4 + r) * 72;
      Pt[pr +  0 + l15] = f2bu(p0);
      Pt[pr + 16 + l15] = f2bu(p1);
      Pt[pr + 32 + l15] = f2bu(p2);
      Pt[pr + 48 + l15] = f2bu(p3);
    }
    // V regs -> LDS
    #pragma unroll
    for(int t = 0; t < 8; t++){
      int qn = (wave * 8 + t) * 64 + lane;
      *(u16x8*)&Vt[qn * 8] = vst[t];
    }
    __syncthreads();   // #1: V staged; K-tile reads done

    // issue K(jt+1) global loads (drain at barrier #2)
    u16x8 kst[8];
    if(jt < 31){
      #pragma unroll
      for(int t = 0; t < 8; t++){
        int qn = (wave * 8 + t) * 64 + lane;
        int j = qn >> 5, cs = qn & 31, cc = cs ^ (j & 7);
        kst[t] = *(const u16x8*)(kb + (size_t)(j0 + 64 + j) * NC + cc * 8);
      }
    }
    // ---- O rescale + PV from LDS ----
    #pragma unroll
    for(int ct = 0; ct < 16; ct++){
      O[ct][0] *= alpha[0]; O[ct][1] *= alpha[1];
      O[ct][2] *= alpha[2]; O[ct][3] *= alpha[3];
    }
    #pragma unroll
    for(int js = 0; js < 2; js++){
      bf16x8 Pf = *(const bf16x8*)&Pt[l15 * 72 + js * 32 + quad * 8];
      #pragma unroll
      for(int ct = 0; ct < 16; ct++){
        int c = ct * 16 + l15;
        int chunk = c * 8 + ((js * 4 + quad) ^ (c & 7));
        O[ct] = MFMA16(Pf, *(const bf16x8*)&Vt[chunk * 8], O[ct]);
      }
    }
    if(jt < 31){
      #pragma unroll
      for(int t = 0; t < 8; t++){
        int qn = (wave * 8 + t) * 64 + lane;
        *(u16x8*)&Kt[qn * 8] = kst[t];
      }
    }
    __syncthreads();   // #2: K(jt+1) staged; V-tile reads done
  }

  // ---- store un-normalized partials ----
  {
    const size_t hb = (size_t)(h * NB + b) * NHW;
    #pragma unroll
    for(int r = 0; r < 4; r++){
      int i = i0 + wave * 16 + quad * 4 + r;
      unsigned short* od = (unsigned short*)Opart + (hb + i) * NC + l15;
      #pragma unroll
      for(int ct = 0; ct < 16; ct++) od[ct * 16] = f2bu(O[ct][r]);
      if(l15 == 0){
        mpart[hb + i] = mr[r];
        lpart[hb + i] = lr[r];
      }
    }
  }
}

// ---------------- flash-decoding combine of the 2 j-halves ----------------
__global__ __launch_bounds__(256)
void flash_combine_kernel(const bf16* __restrict__ Opart, const float* __restrict__ mpart,
                          const float* __restrict__ lpart, bf16* __restrict__ attn){
  int t = blockIdx.x * 256 + threadIdx.x;     // NB*NHW*8 = 131072 threads
  int ng = t >> 3;
  int c0 = (t & 7) * 32;
  const int HS = NB * NHW;
  float m0 = mpart[ng], m1 = mpart[HS + ng];
  float l0 = lpart[ng], l1 = lpart[HS + ng];
  float ms = fmaxf(m0, m1);
  float e0 = __expf(m0 - ms), e1 = __expf(m1 - ms);
  float inv = 1.f / (e0 * l0 + e1 * l1);
  float w0 = e0 * inv, w1 = e1 * inv;
  const unsigned short* O0 = (const unsigned short*)Opart + (size_t)ng * NC + c0;
  const unsigned short* O1 = O0 + (size_t)HS * NC;
  unsigned short* dst = (unsigned short*)attn + (size_t)ng * NC + c0;
  #pragma unroll
  for(int u = 0; u < 32; u += 8){
    u16x8 a = *(const u16x8*)(O0 + u);
    u16x8 bv = *(const u16x8*)(O1 + u);
    u16x8 o;
    #pragma unroll
    for(int e = 0; e < 8; e++)
      o[e] = f2bu(w0 * u2f(((unsigned short*)&a)[e]) + w1 * u2f(((unsigned short*)&bv)[e]));
    *(u16x8*)(dst + u) = o;
  }
}

extern "C" void kernel_launch(void* const* d_in, const int* in_sizes, int n_in,
                              void* d_out, int out_size, void* d_ws, size_t ws_size,
                              hipStream_t stream){
  (void)in_sizes; (void)n_in; (void)out_size; (void)ws_size;
  const float* x        = (const float*)d_in[0];
  const float* gn_scale = (const float*)d_in[1];
  const float* gn_bias  = (const float*)d_in[2];
  const float* wq = (const float*)d_in[3];  const float* bq = (const float*)d_in[4];
  const float* wk = (const float*)d_in[5];  const float* bk = (const float*)d_in[6];
  const float* wv = (const float*)d_in[7];  const float* bv = (const float*)d_in[8];
  const float* wp = (const float*)d_in[9];  const float* bp = (const float*)d_in[10];
  float* out = (float*)d_out;

  char* ws = (char*)d_ws;
  const size_t TEN = (size_t)NB * NC * NHW;           // 4194304
  float* stats = (float*)ws;                           // 1 KB
  bf16* q     = (bf16*)(ws + 1024);                    // [B][n][C] (scaled by 1/16)
  bf16* k     = (bf16*)(ws + 1024 + 1 * TEN * 2);      // [B][n][C]
  bf16* v     = (bf16*)(ws + 1024 + 2 * TEN * 2);      // [B][C][n]
  bf16* Opart = (bf16*)(ws + 1024 + 3 * TEN * 2);      // [2][B][n][C]  16.8 MB
  float* mpart = (float*)(ws + 1024 + 5 * TEN * 2);    // [2][B][n]
  float* lpart = (float*)(ws + 1024 + 5 * TEN * 2 + 2 * NB * NHW * 4);
  bf16* attn  = q;                                     // alias: q dead after flash

  gn_stats_kernel<<<128, 256, 0, stream>>>(x, stats);

  dim3 cgrid(NHW / 64, NC / 64, NB);
  conv1x1_kernel<float, bf16><<<cgrid, 256, 0, stream>>>(
      wq, x, bq, nullptr, stats, gn_scale, gn_bias, q, 1, 1, 0, 0.0625f);
  conv1x1_kernel<float, bf16><<<cgrid, 256, 0, stream>>>(
      wk, x, bk, nullptr, stats, gn_scale, gn_bias, k, 1, 1, 0, 1.0f);
  conv1x1_kernel<float, bf16><<<cgrid, 256, 0, stream>>>(
      wv, x, bv, nullptr, stats, gn_scale, gn_bias, v, 0, 1, 0, 1.0f);

  flash_mfma2_kernel<<<dim3(NHW / 64, NB, 2), 256, 0, stream>>>(
      q, k, v, Opart, mpart, lpart);
  flash_combine_kernel<<<(NB * NHW * 8) / 256, 256, 0, stream>>>(
      Opart, mpart, lpart, attn);

  conv1x1_kernel<bf16, float><<<cgrid, 256, 0, stream>>>(
      wp, attn, bp, x, nullptr, nullptr, nullptr, out, 0, 0, 1, 1.0f);
}

// Round 6
// 334.302 us; speedup vs baseline: 5.2286x; 1.3558x over previous
//
#include <hip/hip_runtime.h>
#include <hip/hip_bf16.h>

#define NB 4
#define NC 256
#define NHW 4096
#define CPG 8
#define GEPS 1e-6f

typedef __hip_bfloat16 bf16;
typedef __attribute__((ext_vector_type(8))) short bf16x8;
typedef __attribute__((ext_vector_type(4))) float f32x4;
typedef __attribute__((ext_vector_type(8))) unsigned short u16x8;

#define MFMA16(A,B,C) __builtin_amdgcn_mfma_f32_16x16x32_bf16(A,B,C,0,0,0)

typedef __attribute__((address_space(1))) const unsigned int as1_uint;
typedef __attribute__((address_space(3))) unsigned int as3_uint;
__device__ __forceinline__ void gload_lds16(const void* g, void* l){
  __builtin_amdgcn_global_load_lds((as1_uint*)g, (as3_uint*)l, 16, 0, 0);
}

__device__ __forceinline__ float u2f(unsigned short u){
  union { unsigned u32; float f; } w; w.u32 = ((unsigned)u) << 16; return w.f;
}
__device__ __forceinline__ bf16 f2b(float v){ return __float2bfloat16(v); }
__device__ __forceinline__ unsigned short f2bu(float v){
  union { bf16 h; unsigned short u; } w; w.h = __float2bfloat16(v); return w.u;
}
__device__ __forceinline__ float4 ld4(const float* p){ return *(const float4*)p; }
__device__ __forceinline__ float4 ld4(const bf16* p){
  ushort4 w = *(const ushort4*)p;
  float4 r; r.x = u2f(w.x); r.y = u2f(w.y); r.z = u2f(w.z); r.w = u2f(w.w); return r;
}
__device__ __forceinline__ void st1(float* p, float v){ *p = v; }
__device__ __forceinline__ void st1(bf16* p, float v){ *p = f2b(v); }

// ---------------- GroupNorm stats ----------------
__global__ __launch_bounds__(256)
void gn_stats_kernel(const float* __restrict__ x, float* __restrict__ stats){
  const int bg = blockIdx.x;
  const float* p = x + (size_t)bg * (CPG * NHW);
  float s = 0.f, s2 = 0.f;
  for(int i = threadIdx.x * 4; i < CPG * NHW; i += 1024){
    float4 v = *(const float4*)(p + i);
    s  += v.x + v.y + v.z + v.w;
    s2 += v.x*v.x + v.y*v.y + v.z*v.z + v.w*v.w;
  }
  __shared__ float red[256];
  red[threadIdx.x] = s; __syncthreads();
  for(int t = 128; t > 0; t >>= 1){
    if(threadIdx.x < t) red[threadIdx.x] += red[threadIdx.x + t];
    __syncthreads();
  }
  float sum = red[0]; __syncthreads();
  red[threadIdx.x] = s2; __syncthreads();
  for(int t = 128; t > 0; t >>= 1){
    if(threadIdx.x < t) red[threadIdx.x] += red[threadIdx.x + t];
    __syncthreads();
  }
  if(threadIdx.x == 0){
    const float inv_n = 1.f / (float)(CPG * NHW);
    float mean = sum * inv_n;
    float var = red[0] * inv_n - mean * mean;
    if(var < 0.f) var = 0.f;
    stats[bg * 2]     = mean;
    stats[bg * 2 + 1] = rsqrtf(var + GEPS);
  }
}

// ---- 1x1 conv GEMM (SIMT) ----
template<typename TSRC, typename TOUT>
__global__ __launch_bounds__(256)
void conv1x1_kernel(const float* __restrict__ W, const TSRC* __restrict__ src,
                    const float* __restrict__ bias, const float* __restrict__ res,
                    const float* __restrict__ stats, const float* __restrict__ gscale,
                    const float* __restrict__ gbias,
                    TOUT* __restrict__ out, int mode, int fuse_gn, int src_nc,
                    float oscale){
  __shared__ __align__(16) float As[16][68];
  __shared__ __align__(16) float Bs[16][68];
  const int b  = blockIdx.z;
  const int nB = blockIdx.x * 64;
  const int oB = blockIdx.y * 64;
  const TSRC* su = src + (size_t)b * NC * NHW;
  const int tid = threadIdx.x;
  const int tx = tid & 15, ty = tid >> 4;
  const int idx4 = tid * 4;
  const int ar = idx4 >> 4, ac = idx4 & 15;
  const int bn = idx4 & 63, bc = idx4 >> 6;
  const int bn2 = tid & 63, g2 = tid >> 6;
  float acc[4][4] = {{0.f}};
  for(int k0 = 0; k0 < NC; k0 += 16){
    float4 a4w = ld4(W + (size_t)(oB + ar) * NC + k0 + ac);
    As[ac + 0][ar] = a4w.x; As[ac + 1][ar] = a4w.y;
    As[ac + 2][ar] = a4w.z; As[ac + 3][ar] = a4w.w;
    if(src_nc){
      float4 t = ld4(su + (size_t)(nB + bn2) * NC + k0 + g2 * 4);
      Bs[g2*4+0][bn2] = t.x; Bs[g2*4+1][bn2] = t.y;
      Bs[g2*4+2][bn2] = t.z; Bs[g2*4+3][bn2] = t.w;
    } else {
      int c = k0 + bc;
      float4 b4 = ld4(su + (size_t)c * NHW + nB + bn);
      if(fuse_gn){
        int bg = (b << 5) | (c >> 3);
        float rstd = stats[bg * 2 + 1];
        float a = rstd * gscale[c];
        float d = gbias[c] - stats[bg * 2] * a;
        b4.x = b4.x * a + d; b4.y = b4.y * a + d;
        b4.z = b4.z * a + d; b4.w = b4.w * a + d;
      }
      *(float4*)&Bs[bc][bn] = b4;
    }
    __syncthreads();
    #pragma unroll
    for(int kk = 0; kk < 16; kk++){
      float4 a4 = *(const float4*)&As[kk][ty * 4];
      float4 q4 = *(const float4*)&Bs[kk][tx * 4];
      float a[4] = {a4.x, a4.y, a4.z, a4.w};
      float bb[4] = {q4.x, q4.y, q4.z, q4.w};
      #pragma unroll
      for(int r = 0; r < 4; r++)
        #pragma unroll
        for(int s = 0; s < 4; s++) acc[r][s] += a[r] * bb[s];
    }
    __syncthreads();
  }
  float bias4[4];
  #pragma unroll
  for(int r = 0; r < 4; r++) bias4[r] = bias[oB + ty * 4 + r];
  if(mode == 0){
    TOUT* ob = out + (size_t)b * NC * NHW;
    const float* rb = res ? res + (size_t)b * NC * NHW : nullptr;
    #pragma unroll
    for(int r = 0; r < 4; r++){
      int o = oB + ty * 4 + r;
      #pragma unroll
      for(int s = 0; s < 4; s++){
        int n = nB + tx * 4 + s;
        float vv = (acc[r][s] + bias4[r]) * oscale;
        if(rb) vv += rb[(size_t)o * NHW + n];
        st1(ob + (size_t)o * NHW + n, vv);
      }
    }
  } else {
    TOUT* ob = out + (size_t)b * NHW * NC;
    #pragma unroll
    for(int s = 0; s < 4; s++){
      int n = nB + tx * 4 + s;
      #pragma unroll
      for(int r = 0; r < 4; r++)
        st1(ob + (size_t)n * NC + oB + ty * 4 + r, (acc[r][s] + bias4[r]) * oscale);
    }
  }
}

// ---------------- MFMA flash, no-max softmax, dbuf global_load_lds ----------------
// q,kt: [B][n][C] (q pre-scaled 1/16)  v: [B][C][n]
// block: 64 Q-rows (4 waves x 16), j-half (h) of 2048 = 64 iters of JT=32.
__global__ __launch_bounds__(256)
void flash_mfma3_kernel(const bf16* __restrict__ qg, const bf16* __restrict__ ktg,
                        const bf16* __restrict__ vg, bf16* __restrict__ Opart,
                        float* __restrict__ lpart){
  const int b  = blockIdx.y;
  const int h  = blockIdx.z;
  const int i0 = blockIdx.x * 64;
  const int tid = threadIdx.x;
  const int wave = tid >> 6, lane = tid & 63;
  const int l15 = lane & 15, quad = lane >> 4;

  __shared__ __align__(16) unsigned short Kt[2][1024 * 8];   // 2 x 16 KB; qn = j*32 + slot
  __shared__ __align__(16) unsigned short Vt[2][1024 * 8];   // 2 x 16 KB; qn = c*4 + slot
  __shared__ __align__(16) unsigned short Pt_all[4][16 * 40]; // 5 KB, per-wave P (PLD=40)
  unsigned short* Pt = Pt_all[wave];

  // Q fragments (B-operand layout = [n=l15][k=quad*8+..], identical regs)
  const short* qp = (const short*)qg + ((size_t)b * NHW + i0 + wave * 16 + l15) * NC + quad * 8;
  bf16x8 Qf[8];
  #pragma unroll
  for(int ks = 0; ks < 8; ks++) Qf[ks] = *(const bf16x8*)(qp + ks * 32);

  const short* kb = (const short*)ktg + ((size_t)b * NHW + h * 2048) * NC;
  const short* vb = (const short*)vg + (size_t)b * NC * NHW + h * 2048;

  f32x4 O[16];
  #pragma unroll
  for(int ct = 0; ct < 16; ct++) O[ct] = (f32x4){0.f, 0.f, 0.f, 0.f};
  float lr = 0.f;

  // prologue: stage tile 0 into buffer 0
  #pragma unroll
  for(int t = 0; t < 4; t++){
    int qb0 = (wave * 4 + t) * 64, qn = qb0 + lane;
    int j = qn >> 5, slot = qn & 31, gc = slot ^ (j & 7);
    gload_lds16(kb + (size_t)j * NC + gc * 8, &Kt[0][(size_t)qb0 * 8]);
  }
  #pragma unroll
  for(int t = 0; t < 4; t++){
    int qb0 = (wave * 4 + t) * 64, qn = qb0 + lane;
    int c = qn >> 2, slot = qn & 3, gc = slot ^ (c & 3);
    gload_lds16(vb + (size_t)c * NHW + gc * 8, &Vt[0][(size_t)qb0 * 8]);
  }

  for(int jt = 0; jt < 64; jt++){
    __syncthreads();                       // drains stage(jt); tiles[p] ready
    const int p = jt & 1;
    if(jt + 1 < 64){
      const int j0n = (jt + 1) * 32;
      #pragma unroll
      for(int t = 0; t < 4; t++){
        int qb0 = (wave * 4 + t) * 64, qn = qb0 + lane;
        int j = qn >> 5, slot = qn & 31, gc = slot ^ (j & 7);
        gload_lds16(kb + (size_t)(j0n + j) * NC + gc * 8, &Kt[p ^ 1][(size_t)qb0 * 8]);
      }
      #pragma unroll
      for(int t = 0; t < 4; t++){
        int qb0 = (wave * 4 + t) * 64, qn = qb0 + lane;
        int c = qn >> 2, slot = qn & 3, gc = slot ^ (c & 3);
        gload_lds16(vb + (size_t)c * NHW + j0n + gc * 8, &Vt[p ^ 1][(size_t)qb0 * 8]);
      }
    }
    // ---- S^T = K.Q^T (swap trick): lane col = i = l15, rows = j ----
    f32x4 S[2];
    #pragma unroll
    for(int st = 0; st < 2; st++){
      S[st] = (f32x4){0.f, 0.f, 0.f, 0.f};
      const int j = st * 16 + l15;
      const unsigned short* kr = &Kt[p][(size_t)j * 256];
      #pragma unroll
      for(int ks = 0; ks < 8; ks++){
        int slot = (ks * 4 + quad) ^ (j & 7);
        S[st] = MFMA16(*(const bf16x8*)&kr[slot * 8], Qf[ks], S[st]);
      }
    }
    // ---- P = exp(S) (no max needed: |S| <= ~7), packed b64 store ----
    #pragma unroll
    for(int st = 0; st < 2; st++){
      float p0 = __expf(S[st][0]), p1 = __expf(S[st][1]);
      float p2 = __expf(S[st][2]), p3 = __expf(S[st][3]);
      lr += (p0 + p1) + (p2 + p3);
      ushort4 pk; pk.x = f2bu(p0); pk.y = f2bu(p1); pk.z = f2bu(p2); pk.w = f2bu(p3);
      *(ushort4*)&Pt[l15 * 40 + st * 16 + quad * 4] = pk;
    }
    // ---- O += P.V^T ----
    bf16x8 Pf = *(const bf16x8*)&Pt[l15 * 40 + quad * 8];
    #pragma unroll
    for(int ct = 0; ct < 16; ct++){
      int c = ct * 16 + l15;
      int slot = quad ^ (c & 3);
      O[ct] = MFMA16(Pf, *(const bf16x8*)&Vt[p][(size_t)(c * 4 + slot) * 8], O[ct]);
    }
  }

  // ---- l reduction across quads (row i = l15) ----
  lr += __shfl_xor(lr, 16);
  lr += __shfl_xor(lr, 32);

  // ---- store un-normalized partials ----
  const size_t hb = (size_t)(h * NB + b) * NHW;
  #pragma unroll
  for(int r = 0; r < 4; r++){
    int i = i0 + wave * 16 + quad * 4 + r;
    unsigned short* od = (unsigned short*)Opart + (hb + i) * NC + l15;
    #pragma unroll
    for(int ct = 0; ct < 16; ct++) od[ct * 16] = f2bu(O[ct][r]);
  }
  if(lane < 16) lpart[hb + i0 + wave * 16 + l15] = lr;
}

// ---------------- combine the 2 j-halves ----------------
__global__ __launch_bounds__(256)
void flash_combine_kernel(const bf16* __restrict__ Opart, const float* __restrict__ lpart,
                          bf16* __restrict__ attn){
  int t = blockIdx.x * 256 + threadIdx.x;     // NB*NHW*8 threads
  int ng = t >> 3;
  int c0 = (t & 7) * 32;
  const int HS = NB * NHW;
  float inv = 1.f / (lpart[ng] + lpart[HS + ng]);
  const unsigned short* O0 = (const unsigned short*)Opart + (size_t)ng * NC + c0;
  const unsigned short* O1 = O0 + (size_t)HS * NC;
  unsigned short* dst = (unsigned short*)attn + (size_t)ng * NC + c0;
  #pragma unroll
  for(int u = 0; u < 32; u += 8){
    u16x8 a = *(const u16x8*)(O0 + u);
    u16x8 bv = *(const u16x8*)(O1 + u);
    u16x8 o;
    #pragma unroll
    for(int e = 0; e < 8; e++)
      o[e] = f2bu((u2f(((unsigned short*)&a)[e]) + u2f(((unsigned short*)&bv)[e])) * inv);
    *(u16x8*)(dst + u) = o;
  }
}

extern "C" void kernel_launch(void* const* d_in, const int* in_sizes, int n_in,
                              void* d_out, int out_size, void* d_ws, size_t ws_size,
                              hipStream_t stream){
  (void)in_sizes; (void)n_in; (void)out_size; (void)ws_size;
  const float* x        = (const float*)d_in[0];
  const float* gn_scale = (const float*)d_in[1];
  const float* gn_bias  = (const float*)d_in[2];
  const float* wq = (const float*)d_in[3];  const float* bq = (const float*)d_in[4];
  const float* wk = (const float*)d_in[5];  const float* bk = (const float*)d_in[6];
  const float* wv = (const float*)d_in[7];  const float* bv = (const float*)d_in[8];
  const float* wp = (const float*)d_in[9];  const float* bp = (const float*)d_in[10];
  float* out = (float*)d_out;

  char* ws = (char*)d_ws;
  const size_t TEN = (size_t)NB * NC * NHW;           // 4194304
  float* stats = (float*)ws;                           // 1 KB
  bf16* q     = (bf16*)(ws + 1024);                    // [B][n][C] (scaled 1/16)
  bf16* k     = (bf16*)(ws + 1024 + 1 * TEN * 2);      // [B][n][C]
  bf16* v     = (bf16*)(ws + 1024 + 2 * TEN * 2);      // [B][C][n]
  bf16* Opart = (bf16*)(ws + 1024 + 3 * TEN * 2);      // [2][B][n][C]
  float* lpart = (float*)(ws + 1024 + 5 * TEN * 2);    // [2][B][n]
  bf16* attn  = q;                                     // alias: q dead after flash

  gn_stats_kernel<<<128, 256, 0, stream>>>(x, stats);

  dim3 cgrid(NHW / 64, NC / 64, NB);
  conv1x1_kernel<float, bf16><<<cgrid, 256, 0, stream>>>(
      wq, x, bq, nullptr, stats, gn_scale, gn_bias, q, 1, 1, 0, 0.0625f);
  conv1x1_kernel<float, bf16><<<cgrid, 256, 0, stream>>>(
      wk, x, bk, nullptr, stats, gn_scale, gn_bias, k, 1, 1, 0, 1.0f);
  conv1x1_kernel<float, bf16><<<cgrid, 256, 0, stream>>>(
      wv, x, bv, nullptr, stats, gn_scale, gn_bias, v, 0, 1, 0, 1.0f);

  flash_mfma3_kernel<<<dim3(NHW / 64, NB, 2), 256, 0, stream>>>(
      q, k, v, Opart, lpart);
  flash_combine_kernel<<<(NB * NHW * 8) / 256, 256, 0, stream>>>(
      Opart, lpart, attn);

  conv1x1_kernel<bf16, float><<<cgrid, 256, 0, stream>>>(
      wp, attn, bp, x, nullptr, nullptr, nullptr, out, 0, 0, 1, 1.0f);
}

// Round 7
// 224.142 us; speedup vs baseline: 7.7983x; 1.4915x over previous
//
#include <hip/hip_runtime.h>
#include <hip/hip_bf16.h>

#define NB 4
#define NC 256
#define NHW 4096
#define CPG 8
#define GEPS 1e-6f

typedef __hip_bfloat16 bf16;
typedef __attribute__((ext_vector_type(8))) short bf16x8;
typedef __attribute__((ext_vector_type(4))) float f32x4;
typedef __attribute__((ext_vector_type(8))) unsigned short u16x8;

#define MFMA16(A,B,C) __builtin_amdgcn_mfma_f32_16x16x32_bf16(A,B,C,0,0,0)

typedef __attribute__((address_space(1))) const unsigned int as1_uint;
typedef __attribute__((address_space(3))) unsigned int as3_uint;
__device__ __forceinline__ void gload_lds16(const void* g, void* l){
  __builtin_amdgcn_global_load_lds((as1_uint*)g, (as3_uint*)l, 16, 0, 0);
}

__device__ __forceinline__ float u2f(unsigned short u){
  union { unsigned u32; float f; } w; w.u32 = ((unsigned)u) << 16; return w.f;
}
__device__ __forceinline__ bf16 f2b(float v){ return __float2bfloat16(v); }
__device__ __forceinline__ unsigned short f2bu(float v){
  union { bf16 h; unsigned short u; } w; w.h = __float2bfloat16(v); return w.u;
}

// ---------------- GroupNorm stats ----------------
__global__ __launch_bounds__(256)
void gn_stats_kernel(const float* __restrict__ x, float* __restrict__ stats){
  const int bg = blockIdx.x;
  const float* p = x + (size_t)bg * (CPG * NHW);
  float s = 0.f, s2 = 0.f;
  for(int i = threadIdx.x * 4; i < CPG * NHW; i += 1024){
    float4 v = *(const float4*)(p + i);
    s  += v.x + v.y + v.z + v.w;
    s2 += v.x*v.x + v.y*v.y + v.z*v.z + v.w*v.w;
  }
  __shared__ float red[256];
  red[threadIdx.x] = s; __syncthreads();
  for(int t = 128; t > 0; t >>= 1){
    if(threadIdx.x < t) red[threadIdx.x] += red[threadIdx.x + t];
    __syncthreads();
  }
  float sum = red[0]; __syncthreads();
  red[threadIdx.x] = s2; __syncthreads();
  for(int t = 128; t > 0; t >>= 1){
    if(threadIdx.x < t) red[threadIdx.x] += red[threadIdx.x + t];
    __syncthreads();
  }
  if(threadIdx.x == 0){
    const float inv_n = 1.f / (float)(CPG * NHW);
    float mean = sum * inv_n;
    float var = red[0] * inv_n - mean * mean;
    if(var < 0.f) var = 0.f;
    stats[bg * 2]     = mean;
    stats[bg * 2 + 1] = rsqrtf(var + GEPS);
  }
}

// ---------------- weight prep: fp32 -> bf16 (+q scale fold) ----------------
__global__ __launch_bounds__(256)
void wprep_kernel(const float* __restrict__ wq, const float* __restrict__ wk,
                  const float* __restrict__ wv, const float* __restrict__ wp,
                  const float* __restrict__ bq, const float* __restrict__ bk,
                  const float* __restrict__ bv,
                  bf16* __restrict__ wqkv, bf16* __restrict__ wpb, float* __restrict__ bqs){
  int i = blockIdx.x * 256 + threadIdx.x;          // grid 1024 -> 262144 threads
  if(i < 196608){
    float v;
    if(i < 65536)       v = wq[i] * 0.0625f;
    else if(i < 131072) v = wk[i - 65536];
    else                v = wv[i - 131072];
    wqkv[i] = f2b(v);
  } else {
    int j = i - 196608;                            // < 65536
    wpb[j] = f2b(wp[j]);
  }
  if(i < 768) bqs[i] = (i < 256) ? bq[i] * 0.0625f : (i < 512 ? bk[i - 256] : bv[i - 512]);
}

// ---------------- GN apply + transpose: xt[b][n][c] = GN(x)[b][c][n], bf16 ----------------
__global__ __launch_bounds__(256)
void gn_prep_kernel(const float* __restrict__ x, const float* __restrict__ stats,
                    const float* __restrict__ gsc, const float* __restrict__ gbi,
                    bf16* __restrict__ xt){
  const int b = blockIdx.z, cB = blockIdx.y * 64, nB = blockIdx.x * 64;
  __shared__ unsigned short Tt[64][80];
  const int tid = threadIdx.x;
  const float* xb = x + ((size_t)(b * NC + cB)) * NHW + nB;
  #pragma unroll
  for(int pass = 0; pass < 4; pass++){
    int c_loc = (tid >> 4) + pass * 16;
    int n0 = (tid & 15) * 4;
    float4 v = *(const float4*)(xb + (size_t)c_loc * NHW + n0);
    int c_abs = cB + c_loc, bg = b * 32 + (c_abs >> 3);
    float a = stats[bg * 2 + 1] * gsc[c_abs];
    float d = gbi[c_abs] - stats[bg * 2] * a;
    Tt[n0 + 0][c_loc] = f2bu(v.x * a + d);
    Tt[n0 + 1][c_loc] = f2bu(v.y * a + d);
    Tt[n0 + 2][c_loc] = f2bu(v.z * a + d);
    Tt[n0 + 3][c_loc] = f2bu(v.w * a + d);
  }
  __syncthreads();
  int n_loc = tid >> 2, cq = (tid & 3) * 16;
  u16x8 w0 = *(const u16x8*)&Tt[n_loc][cq];
  u16x8 w1 = *(const u16x8*)&Tt[n_loc][cq + 8];
  unsigned short* dst = (unsigned short*)xt + ((size_t)(b * NHW + nB + n_loc)) * NC + cB + cq;
  *(u16x8*)dst = w0;
  *(u16x8*)(dst + 8) = w1;
}

// ---------------- MFMA GEMM: D[o][n] = W[o][:]·Bm[n][:] + bias[o] ----------------
// epi 0 (qkv): oB<256 -> qo [n][C]; <512 -> ko [n][C]; else vo [b][c][n]  (bf16)
// epi 1 (proj): fo [b][c][n] fp32 = acc + bias + xres
__global__ __launch_bounds__(256, 2)
void gemm_kernel(const bf16* __restrict__ Wb, const bf16* __restrict__ Bm,
                 const float* __restrict__ bias,
                 bf16* __restrict__ qo, bf16* __restrict__ ko, bf16* __restrict__ vo,
                 float* __restrict__ fo, const float* __restrict__ xres, int epi){
  const int nB = blockIdx.x * 128;
  const int oB = blockIdx.y * 128;
  const int tid = threadIdx.x;
  const int wave = tid >> 6, lane = tid & 63;
  const int l15 = lane & 15, quad = lane >> 4;
  const int wx = wave & 1, wy = wave >> 1;

  __shared__ __align__(16) unsigned short Ast[2][512 * 8];
  __shared__ __align__(16) unsigned short Bst[2][512 * 8];
  __shared__ __align__(16) unsigned short Tt[128 * 136];

  const short* Wp = (const short*)Wb;
  const short* Bp = (const short*)Bm;

  f32x4 acc[4][4];
  #pragma unroll
  for(int mi = 0; mi < 4; mi++)
    #pragma unroll
    for(int ni = 0; ni < 4; ni++) acc[mi][ni] = (f32x4){0.f, 0.f, 0.f, 0.f};

  // prologue stage k0 = 0 into buf 0
  #pragma unroll
  for(int t = 0; t < 2; t++){
    int qn0 = (wave * 2 + t) * 64, qn = qn0 + lane;
    int o = qn >> 2, slot = qn & 3;
    gload_lds16(Wp + (size_t)(oB + o) * NC + ((slot ^ (o & 3)) * 8), &Ast[0][qn0 * 8]);
  }
  #pragma unroll
  for(int t = 0; t < 2; t++){
    int qn0 = (wave * 2 + t) * 64, qn = qn0 + lane;
    int n = qn >> 2, slot = qn & 3;
    gload_lds16(Bp + (size_t)(nB + n) * NC + ((slot ^ (n & 3)) * 8), &Bst[0][qn0 * 8]);
  }

  for(int kt = 0; kt < 8; kt++){
    __syncthreads();
    const int p = kt & 1;
    if(kt < 7){
      const int k0 = (kt + 1) * 32;
      #pragma unroll
      for(int t = 0; t < 2; t++){
        int qn0 = (wave * 2 + t) * 64, qn = qn0 + lane;
        int o = qn >> 2, slot = qn & 3;
        gload_lds16(Wp + (size_t)(oB + o) * NC + k0 + ((slot ^ (o & 3)) * 8), &Ast[p ^ 1][qn0 * 8]);
      }
      #pragma unroll
      for(int t = 0; t < 2; t++){
        int qn0 = (wave * 2 + t) * 64, qn = qn0 + lane;
        int n = qn >> 2, slot = qn & 3;
        gload_lds16(Bp + (size_t)(nB + n) * NC + k0 + ((slot ^ (n & 3)) * 8), &Bst[p ^ 1][qn0 * 8]);
      }
    }
    bf16x8 Af[4], Bf[4];
    #pragma unroll
    for(int mi = 0; mi < 4; mi++){
      int o = wx * 64 + mi * 16 + l15;
      Af[mi] = *(const bf16x8*)&Ast[p][(o * 4 + (quad ^ (o & 3))) * 8];
    }
    #pragma unroll
    for(int ni = 0; ni < 4; ni++){
      int n = wy * 64 + ni * 16 + l15;
      Bf[ni] = *(const bf16x8*)&Bst[p][(n * 4 + (quad ^ (n & 3))) * 8];
    }
    #pragma unroll
    for(int mi = 0; mi < 4; mi++)
      #pragma unroll
      for(int ni = 0; ni < 4; ni++)
        acc[mi][ni] = MFMA16(Af[mi], Bf[ni], acc[mi][ni]);
  }

  float bi[4][4];
  #pragma unroll
  for(int mi = 0; mi < 4; mi++)
    #pragma unroll
    for(int r = 0; r < 4; r++)
      bi[mi][r] = bias[oB + wx * 64 + mi * 16 + quad * 4 + r];

  if(epi == 1){
    #pragma unroll
    for(int mi = 0; mi < 4; mi++){
      #pragma unroll
      for(int ni = 0; ni < 4; ni++){
        int na = nB + wy * 64 + ni * 16 + l15;
        #pragma unroll
        for(int r = 0; r < 4; r++){
          int c = oB + wx * 64 + mi * 16 + quad * 4 + r;
          size_t idx = ((size_t)(na >> 12) * NC + c) * NHW + (na & 4095);
          fo[idx] = acc[mi][ni][r] + bi[mi][r] + xres[idx];
        }
      }
    }
  } else if(oB >= 512){
    #pragma unroll
    for(int mi = 0; mi < 4; mi++){
      #pragma unroll
      for(int ni = 0; ni < 4; ni++){
        int na = nB + wy * 64 + ni * 16 + l15;
        #pragma unroll
        for(int r = 0; r < 4; r++){
          int c = oB - 512 + wx * 64 + mi * 16 + quad * 4 + r;
          vo[((size_t)(na >> 12) * NC + c) * NHW + (na & 4095)] = f2b(acc[mi][ni][r] + bi[mi][r]);
        }
      }
    }
  } else {
    // q/k: transpose through LDS, write [n][C]
    #pragma unroll
    for(int mi = 0; mi < 4; mi++){
      int ob = wx * 64 + mi * 16 + quad * 4;
      #pragma unroll
      for(int ni = 0; ni < 4; ni++){
        int nl = wy * 64 + ni * 16 + l15;
        ushort4 pk;
        pk.x = f2bu(acc[mi][ni][0] + bi[mi][0]);
        pk.y = f2bu(acc[mi][ni][1] + bi[mi][1]);
        pk.z = f2bu(acc[mi][ni][2] + bi[mi][2]);
        pk.w = f2bu(acc[mi][ni][3] + bi[mi][3]);
        *(ushort4*)&Tt[nl * 136 + ob] = pk;
      }
    }
    __syncthreads();
    bf16* dst = (oB < 256) ? qo : ko;
    const int oc0 = oB & 255;      // 0/128 for q, 256/384 -> 0/128 for k
    int row = tid >> 1, half = tid & 1;
    unsigned short* gp = (unsigned short*)dst + (size_t)(nB + row) * NC + oc0 + half * 64;
    #pragma unroll
    for(int j = 0; j < 8; j++){
      u16x8 w = *(const u16x8*)&Tt[row * 136 + half * 64 + j * 8];
      *(u16x8*)(gp + j * 8) = w;
    }
  }
}

// ---------------- MFMA flash: i=32/wave, jsplit=4, no-max softmax ----------------
// q,kt: [B][n][C] (q pre-scaled 1/16)  v: [B][C][n]
__global__ __launch_bounds__(256, 2)
void flash_mfma4_kernel(const bf16* __restrict__ qg, const bf16* __restrict__ ktg,
                        const bf16* __restrict__ vg, bf16* __restrict__ Opart,
                        float* __restrict__ lpart){
  const int b = blockIdx.y, h = blockIdx.z;
  const int i0 = blockIdx.x * 128;
  const int tid = threadIdx.x;
  const int wave = tid >> 6, lane = tid & 63;
  const int l15 = lane & 15, quad = lane >> 4;

  __shared__ __align__(16) unsigned short Kt[2][1024 * 8];   // 2 x 16 KB
  __shared__ __align__(16) unsigned short Vt[2][1024 * 8];   // 2 x 16 KB
  __shared__ __align__(16) unsigned short Pt_all[4][32 * 40];
  unsigned short* Pt = Pt_all[wave];

  bf16x8 Qf[2][8];
  #pragma unroll
  for(int ist = 0; ist < 2; ist++){
    const short* qp = (const short*)qg +
        ((size_t)b * NHW + i0 + wave * 32 + ist * 16 + l15) * NC + quad * 8;
    #pragma unroll
    for(int ks = 0; ks < 8; ks++) Qf[ist][ks] = *(const bf16x8*)(qp + ks * 32);
  }

  const short* kb = (const short*)ktg + ((size_t)b * NHW + h * 1024) * NC;
  const short* vb = (const short*)vg + (size_t)b * NC * NHW + h * 1024;

  f32x4 O[2][16];
  #pragma unroll
  for(int ist = 0; ist < 2; ist++)
    #pragma unroll
    for(int ct = 0; ct < 16; ct++) O[ist][ct] = (f32x4){0.f, 0.f, 0.f, 0.f};
  float lr0 = 0.f, lr1 = 0.f;

  // prologue: stage tile 0
  #pragma unroll
  for(int t = 0; t < 4; t++){
    int qn0 = (wave * 4 + t) * 64, qn = qn0 + lane;
    int j = qn >> 5, slot = qn & 31;
    gload_lds16(kb + (size_t)j * NC + ((slot ^ (j & 7)) * 8), &Kt[0][qn0 * 8]);
  }
  #pragma unroll
  for(int t = 0; t < 4; t++){
    int qn0 = (wave * 4 + t) * 64, qn = qn0 + lane;
    int c = qn >> 2, slot = qn & 3;
    gload_lds16(vb + (size_t)c * NHW + ((slot ^ (c & 3)) * 8), &Vt[0][qn0 * 8]);
  }

  for(int jt = 0; jt < 32; jt++){
    __syncthreads();
    const int p = jt & 1;
    if(jt < 31){
      const int j0n = (jt + 1) * 32;
      #pragma unroll
      for(int t = 0; t < 4; t++){
        int qn0 = (wave * 4 + t) * 64, qn = qn0 + lane;
        int j = qn >> 5, slot = qn & 31;
        gload_lds16(kb + (size_t)(j0n + j) * NC + ((slot ^ (j & 7)) * 8), &Kt[p ^ 1][qn0 * 8]);
      }
      #pragma unroll
      for(int t = 0; t < 4; t++){
        int qn0 = (wave * 4 + t) * 64, qn = qn0 + lane;
        int c = qn >> 2, slot = qn & 3;
        gload_lds16(vb + (size_t)c * NHW + j0n + ((slot ^ (c & 3)) * 8), &Vt[p ^ 1][qn0 * 8]);
      }
    }
    // ---- S^T = K·Q^T for both i-subtiles (K-frag read once) ----
    f32x4 S[2][2];
    #pragma unroll
    for(int st = 0; st < 2; st++){
      S[st][0] = (f32x4){0.f, 0.f, 0.f, 0.f};
      S[st][1] = (f32x4){0.f, 0.f, 0.f, 0.f};
      const int j = st * 16 + l15;
      const unsigned short* kr = &Kt[p][(size_t)j * 256];
      #pragma unroll
      for(int ks = 0; ks < 8; ks++){
        int slot = (ks * 4 + quad) ^ (j & 7);
        bf16x8 kf = *(const bf16x8*)&kr[slot * 8];
        S[st][0] = MFMA16(kf, Qf[0][ks], S[st][0]);
        S[st][1] = MFMA16(kf, Qf[1][ks], S[st][1]);
      }
    }
    // ---- P = exp(S), accumulate row sums, store A-layout ----
    #pragma unroll
    for(int ist = 0; ist < 2; ist++){
      #pragma unroll
      for(int st = 0; st < 2; st++){
        f32x4 sv = S[st][ist];
        float p0 = __expf(sv[0]), p1 = __expf(sv[1]);
        float p2 = __expf(sv[2]), p3 = __expf(sv[3]);
        if(ist == 0) lr0 += (p0 + p1) + (p2 + p3);
        else         lr1 += (p0 + p1) + (p2 + p3);
        ushort4 pk; pk.x = f2bu(p0); pk.y = f2bu(p1); pk.z = f2bu(p2); pk.w = f2bu(p3);
        *(ushort4*)&Pt[(ist * 16 + l15) * 40 + st * 16 + quad * 4] = pk;
      }
    }
    // ---- O += P·V^T (V-frag read once, both i-subtiles) ----
    bf16x8 Pf0 = *(const bf16x8*)&Pt[(l15) * 40 + quad * 8];
    bf16x8 Pf1 = *(const bf16x8*)&Pt[(16 + l15) * 40 + quad * 8];
    #pragma unroll
    for(int ct = 0; ct < 16; ct++){
      int c = ct * 16 + l15;
      bf16x8 vf = *(const bf16x8*)&Vt[p][(c * 4 + (quad ^ (c & 3))) * 8];
      O[0][ct] = MFMA16(Pf0, vf, O[0][ct]);
      O[1][ct] = MFMA16(Pf1, vf, O[1][ct]);
    }
  }

  lr0 += __shfl_xor(lr0, 16); lr0 += __shfl_xor(lr0, 32);
  lr1 += __shfl_xor(lr1, 16); lr1 += __shfl_xor(lr1, 32);

  const size_t hb = (size_t)(h * NB + b) * NHW;
  #pragma unroll
  for(int ist = 0; ist < 2; ist++){
    #pragma unroll
    for(int r = 0; r < 4; r++){
      int i = i0 + wave * 32 + ist * 16 + quad * 4 + r;
      unsigned short* od = (unsigned short*)Opart + (hb + i) * NC + l15;
      #pragma unroll
      for(int ct = 0; ct < 16; ct++) od[ct * 16] = f2bu(O[ist][ct][r]);
    }
  }
  if(lane < 16){
    lpart[hb + i0 + wave * 32 + l15]      = lr0;
    lpart[hb + i0 + wave * 32 + 16 + l15] = lr1;
  }
}

// ---------------- combine the 4 j-quarters ----------------
__global__ __launch_bounds__(256)
void flash_combine4_kernel(const bf16* __restrict__ Opart, const float* __restrict__ lpart,
                           bf16* __restrict__ attn){
  int t = blockIdx.x * 256 + threadIdx.x;     // NB*NHW*8 threads
  int ng = t >> 3;
  int c0 = (t & 7) * 32;
  const int HS = NB * NHW;
  float l = lpart[ng] + lpart[HS + ng] + lpart[2 * HS + ng] + lpart[3 * HS + ng];
  float inv = 1.f / l;
  const unsigned short* O0 = (const unsigned short*)Opart + (size_t)ng * NC + c0;
  unsigned short* dst = (unsigned short*)attn + (size_t)ng * NC + c0;
  #pragma unroll
  for(int u = 0; u < 32; u += 8){
    u16x8 a0 = *(const u16x8*)(O0 + u);
    u16x8 a1 = *(const u16x8*)(O0 + (size_t)HS * NC + u);
    u16x8 a2 = *(const u16x8*)(O0 + (size_t)2 * HS * NC + u);
    u16x8 a3 = *(const u16x8*)(O0 + (size_t)3 * HS * NC + u);
    u16x8 o;
    #pragma unroll
    for(int e = 0; e < 8; e++)
      o[e] = f2bu((u2f(a0[e]) + u2f(a1[e]) + u2f(a2[e]) + u2f(a3[e])) * inv);
    *(u16x8*)(dst + u) = o;
  }
}

extern "C" void kernel_launch(void* const* d_in, const int* in_sizes, int n_in,
                              void* d_out, int out_size, void* d_ws, size_t ws_size,
                              hipStream_t stream){
  (void)in_sizes; (void)n_in; (void)out_size; (void)ws_size;
  const float* x        = (const float*)d_in[0];
  const float* gn_scale = (const float*)d_in[1];
  const float* gn_bias  = (const float*)d_in[2];
  const float* wq = (const float*)d_in[3];  const float* bq = (const float*)d_in[4];
  const float* wk = (const float*)d_in[5];  const float* bk = (const float*)d_in[6];
  const float* wv = (const float*)d_in[7];  const float* bv = (const float*)d_in[8];
  const float* wp = (const float*)d_in[9];  const float* bp = (const float*)d_in[10];
  float* out = (float*)d_out;

  char* ws = (char*)d_ws;
  const size_t MB = 1048576;
  float* stats = (float*)ws;                         // 1 KB
  float* bqs   = (float*)(ws + 4096);                // 3 KB
  bf16* wqkv   = (bf16*)(ws + 8192);                 // 384 KB
  bf16* wpb    = (bf16*)(ws + 8192 + 393216);        // 128 KB
  bf16* xt     = (bf16*)(ws + 1 * MB);               // 8 MB (region reserved 32 MB)
  bf16* Opart  = xt;                                 // alias: xt dead after qkv gemm
  bf16* q      = (bf16*)(ws + 33 * MB);              // 8 MB
  bf16* k      = (bf16*)(ws + 41 * MB);              // 8 MB
  bf16* v      = (bf16*)(ws + 49 * MB);              // 8 MB
  float* lpart = (float*)(ws + 57 * MB);             // 256 KB
  bf16* attn   = q;                                  // alias: q dead after flash

  gn_stats_kernel<<<128, 256, 0, stream>>>(x, stats);
  wprep_kernel<<<1024, 256, 0, stream>>>(wq, wk, wv, wp, bq, bk, bv, wqkv, wpb, bqs);
  gn_prep_kernel<<<dim3(64, 4, NB), 256, 0, stream>>>(x, stats, gn_scale, gn_bias, xt);

  gemm_kernel<<<dim3(128, 6), 256, 0, stream>>>(
      wqkv, xt, bqs, q, k, v, nullptr, nullptr, 0);

  flash_mfma4_kernel<<<dim3(32, NB, 4), 256, 0, stream>>>(q, k, v, Opart, lpart);
  flash_combine4_kernel<<<512, 256, 0, stream>>>(Opart, lpart, attn);

  gemm_kernel<<<dim3(128, 2), 256, 0, stream>>>(
      wpb, attn, bp, nullptr, nullptr, nullptr, out, x, 1);
}